// Round 1
// baseline (12848.752 us; speedup 1.0000x reference)
//
#include <hip/hip_runtime.h>
#include <hip/hip_bf16.h>

#define T_SEQ 512
#define BATCH 256
#define HID   1024
#define EMBD  256
#define NCLS  10

typedef __bf16 bf16x8 __attribute__((ext_vector_type(8)));
typedef float  floatx4 __attribute__((ext_vector_type(4)));

__device__ __forceinline__ unsigned short f2bf(float f) {
    unsigned int u = __builtin_bit_cast(unsigned int, f);
    u += 0x7fffu + ((u >> 16) & 1u);
    return (unsigned short)(u >> 16);
}
__device__ __forceinline__ float bf2f(unsigned short h) {
    unsigned int u = ((unsigned int)h) << 16;
    return __builtin_bit_cast(float, u);
}
__device__ __forceinline__ float sig_fast(float x) {
    return __builtin_amdgcn_rcpf(1.0f + __expf(-x));
}
__device__ __forceinline__ float tanh_fast(float x) {
    return 1.0f - 2.0f * __builtin_amdgcn_rcpf(1.0f + __expf(2.0f * x));
}

struct GridBar {
    unsigned int count;
    unsigned int pad0[31];
    unsigned int flag;
    unsigned int pad1[31];
};

// -------------------- prep: XW[tok][gate][n] = emb[tok] @ Wx_gate + b_gate ---
__global__ void prep_xw_kernel(const float* __restrict__ emb,
                               const float* __restrict__ wgx, const float* __restrict__ wix,
                               const float* __restrict__ wfx, const float* __restrict__ wox,
                               const float* __restrict__ bg,  const float* __restrict__ bi,
                               const float* __restrict__ bf,  const float* __restrict__ bo,
                               float* __restrict__ XW) {
    int gid = blockIdx.x * blockDim.x + threadIdx.x;     // 3*4*1024 = 12288
    if (gid >= 3 * 4 * HID) return;
    int tok  = gid >> 12;
    int gate = (gid >> 10) & 3;
    int n    = gid & 1023;
    const float* W = gate == 0 ? wgx : gate == 1 ? wix : gate == 2 ? wfx : wox;
    const float* B = gate == 0 ? bg  : gate == 1 ? bi  : gate == 2 ? bf  : bo;
    float acc = B[n];
    const float* e = emb + tok * EMBD;
    for (int k = 0; k < EMBD; ++k) acc += e[k] * W[k * HID + n];
    XW[gid] = acc;
}

// ------ prep: Wt[(jg*64 + gate*16 + jj)*1024 + k] = bf16(Wh_gate[k][jg*16+jj]) ------
__global__ void prep_w_kernel(const float* __restrict__ wgh, const float* __restrict__ wih,
                              const float* __restrict__ wfh, const float* __restrict__ woh,
                              unsigned short* __restrict__ Wt) {
    __shared__ float tile[64 * 65];
    int bid  = blockIdx.x;          // 4 gates * 16 * 16 = 1024 blocks
    int gate = bid >> 8;
    int k0   = ((bid >> 4) & 15) * 64;
    int j0   = (bid & 15) * 64;
    const float* W = gate == 0 ? wgh : gate == 1 ? wih : gate == 2 ? wfh : woh;
    for (int i = threadIdx.x; i < 4096; i += 256) {
        int kk = i >> 6, jj = i & 63;
        tile[kk * 65 + jj] = W[(k0 + kk) * HID + j0 + jj];   // coalesced on jj
    }
    __syncthreads();
    for (int i = threadIdx.x; i < 4096; i += 256) {
        int jl = i >> 6, kl = i & 63;
        int j = j0 + jl;
        int col = (j >> 4) * 64 + gate * 16 + (j & 15);      // jg*64 + gate*16 + jj
        Wt[col * HID + k0 + kl] = f2bf(tile[kl * 65 + jl]);  // coalesced on kl
    }
}

// -------------------- device-scope barrier (256 arrivals per generation) ----
__device__ __forceinline__ void grid_barrier(GridBar* bar, unsigned int gen) {
    __syncthreads();
    if (threadIdx.x == 0) {
        __threadfence();   // release h stores (wbl2 for cross-XCD visibility)
        unsigned int prev = __hip_atomic_fetch_add(&bar->count, 1u,
                                                   __ATOMIC_RELAXED, __HIP_MEMORY_SCOPE_AGENT);
        if (prev + 1u == gen * 256u) {
            __hip_atomic_store(&bar->flag, gen, __ATOMIC_RELEASE, __HIP_MEMORY_SCOPE_AGENT);
        } else {
            while (__hip_atomic_load(&bar->flag, __ATOMIC_RELAXED,
                                     __HIP_MEMORY_SCOPE_AGENT) < gen) {
                __builtin_amdgcn_s_sleep(8);
            }
        }
        __threadfence();   // acquire (invalidate stale L1/L2 lines)
    }
    __syncthreads();
}

// -------------------- persistent recurrent kernel ---------------------------
// grid 256 (cooperative, 1 WG/CU): bg = blockIdx>>6 (64 batch rows),
// jg = blockIdx&63 (16 hidden cols, all 4 gates => 64 output cols).
__global__ __launch_bounds__(256, 1)
void lstm_kernel(const int* __restrict__ x, const float* __restrict__ XW,
                 const unsigned short* __restrict__ Wt,
                 unsigned short* __restrict__ hbuf, GridBar* bar) {
    __shared__ unsigned short Wl[64 * 1032];   // [col][k] bf16, +8 pad per row (132096 B)
    __shared__ float gbuf[64 * 68];            // [row][col] gate pre-acts     (17408 B)
    __shared__ float xwl[192];                 // [tok][gate][jj]              (768 B)

    const int tid = threadIdx.x;
    const int bg  = blockIdx.x >> 6;
    const int jg  = blockIdx.x & 63;

    // one-time: stage W slice into LDS (16B vector copies, coalesced)
    for (int i = tid; i < 8192; i += 256) {
        int col = i >> 7;
        int kc  = (i & 127) << 3;
        *(uint4*)&Wl[col * 1032 + kc] = *(const uint4*)&Wt[(jg * 64 + col) * HID + kc];
    }
    for (int i = tid; i < 192; i += 256) {
        int tok = i >> 6, g = (i >> 4) & 3, jj = i & 15;
        xwl[i] = XW[(tok * 4 + g) * HID + jg * 16 + jj];
    }
    __syncthreads();

    // MFMA identities
    const int wave = tid >> 6;
    const int lane = tid & 63;
    const int q    = lane >> 4;
    const int m    = lane & 15;
    const int r0   = (wave >> 1) * 32;   // wave row offset within 64
    const int c0   = (wave & 1) * 32;    // wave col offset within 64

    // elementwise ownership: thread -> rows rb..rb+3, col jj (stable over t)
    const int jj = tid & 15;
    const int rb = (tid >> 4) * 4;
    float cst[4] = {0.f, 0.f, 0.f, 0.f};

    for (int t = 0; t < T_SEQ; ++t) {
        const unsigned short* hprev = hbuf + (t & 1) * (BATCH * HID);
        unsigned short*       hnext = hbuf + ((t + 1) & 1) * (BATCH * HID);

        // GEMM: out[64,64] = h[64,1024] @ Wl[1024,64]
        floatx4 acc00 = {0,0,0,0}, acc01 = {0,0,0,0}, acc10 = {0,0,0,0}, acc11 = {0,0,0,0};
        const unsigned short* a0p = hprev + (bg * 64 + r0 + m) * HID + q * 8;
        const unsigned short* a1p = a0p + 16 * HID;
        const unsigned short* b0p = &Wl[(c0 + m) * 1032 + q * 8];
        const unsigned short* b1p = b0p + 16 * 1032;
        #pragma unroll 4
        for (int kb = 0; kb < 32; ++kb) {
            bf16x8 a0 = *(const bf16x8*)(a0p + kb * 32);
            bf16x8 a1 = *(const bf16x8*)(a1p + kb * 32);
            bf16x8 b0 = *(const bf16x8*)(b0p + kb * 32);
            bf16x8 b1 = *(const bf16x8*)(b1p + kb * 32);
            acc00 = __builtin_amdgcn_mfma_f32_16x16x32_bf16(a0, b0, acc00, 0, 0, 0);
            acc01 = __builtin_amdgcn_mfma_f32_16x16x32_bf16(a0, b1, acc01, 0, 0, 0);
            acc10 = __builtin_amdgcn_mfma_f32_16x16x32_bf16(a1, b0, acc10, 0, 0, 0);
            acc11 = __builtin_amdgcn_mfma_f32_16x16x32_bf16(a1, b1, acc11, 0, 0, 0);
        }

        // scatter C (col=lane&15, row=quad*4+reg) into LDS gate buffer
        {
            int row0 = r0 + 4 * q;
            int colb = c0 + m;
            #pragma unroll
            for (int rr = 0; rr < 4; ++rr) {
                gbuf[(row0 + rr) * 68 + colb]           = acc00[rr];
                gbuf[(row0 + rr) * 68 + colb + 16]      = acc01[rr];
                gbuf[(row0 + 16 + rr) * 68 + colb]      = acc10[rr];
                gbuf[(row0 + 16 + rr) * 68 + colb + 16] = acc11[rr];
            }
        }
        __syncthreads();

        // elementwise LSTM cell update
        #pragma unroll
        for (int rr = 0; rr < 4; ++rr) {
            int row = rb + rr;
            int tk  = x[(bg * 64 + row) * T_SEQ + t];
            float ag = gbuf[row * 68 + jj]      + xwl[tk * 64 + jj];
            float ai = gbuf[row * 68 + 16 + jj] + xwl[tk * 64 + 16 + jj];
            float af = gbuf[row * 68 + 32 + jj] + xwl[tk * 64 + 32 + jj];
            float ao = gbuf[row * 68 + 48 + jj] + xwl[tk * 64 + 48 + jj];
            float g  = tanh_fast(ag);
            float ii = sig_fast(ai);
            float ff = sig_fast(af);
            float oo = sig_fast(ao);
            float cn = g * ii + cst[rr] * ff;
            float h  = tanh_fast(cn) * oo;
            cst[rr]  = (tk != 0) ? cn : 0.0f;      // pad = ((x+1)//2) in {0,1,1}
            hnext[(bg * 64 + row) * HID + jg * 16 + jj] = f2bf(h);
        }

        if (t < T_SEQ - 1) grid_barrier(bar, (unsigned int)(t + 1));
    }
}

// -------------------- projection + log_softmax over batch dim ---------------
__global__ void proj_kernel(const unsigned short* __restrict__ h,
                            const float* __restrict__ wph, const float* __restrict__ bp,
                            float* __restrict__ out) {
    __shared__ float wl[HID * NCLS];
    __shared__ float red[256];
    int tid = threadIdx.x;      // = batch row
    for (int i = tid; i < HID * NCLS; i += 256) wl[i] = wph[i];
    __syncthreads();
    float p[NCLS];
    #pragma unroll
    for (int c2 = 0; c2 < NCLS; ++c2) p[c2] = bp[c2];
    const unsigned short* hr = h + tid * HID;
    for (int k0 = 0; k0 < HID / 8; ++k0) {
        bf16x8 hv = *(const bf16x8*)(hr + k0 * 8);
        #pragma unroll
        for (int j = 0; j < 8; ++j) {
            float hk = (float)hv[j];
            #pragma unroll
            for (int c2 = 0; c2 < NCLS; ++c2) p[c2] += hk * wl[(k0 * 8 + j) * NCLS + c2];
        }
    }
    for (int c2 = 0; c2 < NCLS; ++c2) {
        red[tid] = p[c2];
        __syncthreads();
        for (int s = 128; s > 0; s >>= 1) {
            if (tid < s) red[tid] = fmaxf(red[tid], red[tid + s]);
            __syncthreads();
        }
        float mx = red[0];
        __syncthreads();
        red[tid] = __expf(p[c2] - mx);
        __syncthreads();
        for (int s = 128; s > 0; s >>= 1) {
            if (tid < s) red[tid] += red[tid + s];
            __syncthreads();
        }
        float lse = mx + __logf(red[0]);
        __syncthreads();
        out[tid * NCLS + c2] = p[c2] - lse;
    }
}

// ----------------------------------------------------------------------------
extern "C" void kernel_launch(void* const* d_in, const int* in_sizes, int n_in,
                              void* d_out, int out_size, void* d_ws, size_t ws_size,
                              hipStream_t stream) {
    const int*   x    = (const int*)d_in[0];
    const float* emb  = (const float*)d_in[1];
    const float* wgx  = (const float*)d_in[2];
    const float* wgh  = (const float*)d_in[3];
    const float* bg_  = (const float*)d_in[4];
    const float* wix  = (const float*)d_in[5];
    const float* wih  = (const float*)d_in[6];
    const float* bi_  = (const float*)d_in[7];
    const float* wfx  = (const float*)d_in[8];
    const float* wfh  = (const float*)d_in[9];
    const float* bf_  = (const float*)d_in[10];
    const float* wox  = (const float*)d_in[11];
    const float* woh  = (const float*)d_in[12];
    const float* bo_  = (const float*)d_in[13];
    const float* wph  = (const float*)d_in[14];
    const float* bp_  = (const float*)d_in[15];
    float* out = (float*)d_out;

    char* w = (char*)d_ws;
    GridBar*        bar  = (GridBar*)w;                                      // 256 B
    float*          XW   = (float*)(w + 256);                                // 48 KB
    unsigned short* Wt   = (unsigned short*)(w + 256 + 49152);               // 8 MB
    unsigned short* hbuf = (unsigned short*)(w + 256 + 49152 + 8388608);     // 1 MB

    hipMemsetAsync(bar, 0, 256, stream);
    hipMemsetAsync(hbuf, 0, BATCH * HID * sizeof(unsigned short), stream);   // h0 = 0

    prep_xw_kernel<<<48, 256, 0, stream>>>(emb, wgx, wix, wfx, wox,
                                           bg_, bi_, bf_, bo_, XW);
    prep_w_kernel<<<1024, 256, 0, stream>>>(wgh, wih, wfh, woh, Wt);

    void* args[] = { (void*)&x, (void*)&XW, (void*)&Wt, (void*)&hbuf, (void*)&bar };
    hipLaunchCooperativeKernel((void*)lstm_kernel, dim3(256), dim3(256), args, 0, stream);

    proj_kernel<<<1, 256, 0, stream>>>(hbuf, wph, bp_, out);
}

// Round 4
// 7163.619 us; speedup vs baseline: 1.7936x; 1.7936x over previous
//
#include <hip/hip_runtime.h>
#include <hip/hip_bf16.h>

#define T_SEQ 512
#define BATCH 256
#define HID   1024
#define EMBD  256
#define NCLS  10

typedef __bf16 bf16x8 __attribute__((ext_vector_type(8)));
typedef float  floatx4 __attribute__((ext_vector_type(4)));
typedef float  floatx2 __attribute__((ext_vector_type(2)));
typedef unsigned short ushortx8 __attribute__((ext_vector_type(8)));

__device__ __forceinline__ unsigned int f2bf(float f) {
    unsigned int u = __builtin_bit_cast(unsigned int, f);
    u += 0x7fffu + ((u >> 16) & 1u);
    return u >> 16;
}
__device__ __forceinline__ float sig_fast(float x) {
    return __builtin_amdgcn_rcpf(1.0f + __expf(-x));
}
__device__ __forceinline__ float tanh_fast(float x) {
    return 1.0f - 2.0f * __builtin_amdgcn_rcpf(1.0f + __expf(2.0f * x));
}

// One barrier object per group (own cachelines). R1-proven construct.
struct GroupBar {
    unsigned int count;
    unsigned int pad0[63];
    unsigned int flag;
    unsigned int pad1[63];
};

// R1-verified barrier pattern, 32 arrivals per generation.
__device__ __forceinline__ void group_barrier(GroupBar* bar, unsigned int gen) {
    __syncthreads();                       // drains each wave's vmcnt before barrier
    if (threadIdx.x == 0) {
        __threadfence();                   // release: h stores -> agent-visible
        unsigned int prev = __hip_atomic_fetch_add(&bar->count, 1u,
                                                   __ATOMIC_RELAXED, __HIP_MEMORY_SCOPE_AGENT);
        if (prev + 1u == gen * 32u) {
            __hip_atomic_store(&bar->flag, gen, __ATOMIC_RELEASE, __HIP_MEMORY_SCOPE_AGENT);
        } else {
            while (__hip_atomic_load(&bar->flag, __ATOMIC_RELAXED,
                                     __HIP_MEMORY_SCOPE_AGENT) < gen) {
                __builtin_amdgcn_s_sleep(8);
            }
        }
        __threadfence();                   // acquire: invalidate stale cache lines
    }
    __syncthreads();
}

// -------------------- prep: XW[tok][gate][n] = emb[tok] @ Wx_gate + b_gate ---
__global__ void prep_xw_kernel(const float* __restrict__ emb,
                               const float* __restrict__ wgx, const float* __restrict__ wix,
                               const float* __restrict__ wfx, const float* __restrict__ wox,
                               const float* __restrict__ bg,  const float* __restrict__ bi,
                               const float* __restrict__ bf,  const float* __restrict__ bo,
                               float* __restrict__ XW) {
    int gid = blockIdx.x * blockDim.x + threadIdx.x;     // 3*4*1024 = 12288
    if (gid >= 3 * 4 * HID) return;
    int tok  = gid >> 12;
    int gate = (gid >> 10) & 3;
    int n    = gid & 1023;
    const float* W = gate == 0 ? wgx : gate == 1 ? wix : gate == 2 ? wfx : wox;
    const float* B = gate == 0 ? bg  : gate == 1 ? bi  : gate == 2 ? bf  : bo;
    float acc = B[n];
    const float* e = emb + tok * EMBD;
    for (int k = 0; k < EMBD; ++k) acc += e[k] * W[k * HID + n];
    XW[gid] = acc;
}

// ---- prep: Wt in MFMA B-fragment order ----
// frag_id(w,g,kb,cf) = ((w*4+g)*32+kb)*2+cf ; Wt[frag_id*512 + lane*8 + e]
//   = bf16( W_g[k = kb*32 + (lane>>4)*8 + e][j = w*32 + cf*16 + (lane&15)] )
__global__ void prep_w_kernel(const float* __restrict__ wgh, const float* __restrict__ wih,
                              const float* __restrict__ wfh, const float* __restrict__ woh,
                              unsigned short* __restrict__ Wt) {
    int bid = blockIdx.x;                 // 4096 = g(4) x kb(32) x w(32)
    int g   = bid >> 10;
    int kb  = (bid >> 5) & 31;
    int w   = bid & 31;
    const float* W = g == 0 ? wgh : g == 1 ? wih : g == 2 ? wfh : woh;
    int t    = threadIdx.x;               // 128
    int cf   = t >> 6;
    int lane = t & 63;
    int q    = lane >> 4;
    int n    = lane & 15;
    int j    = w * 32 + cf * 16 + n;
    int k0   = kb * 32 + q * 8;
    ushortx8 o8;
    #pragma unroll
    for (int e = 0; e < 8; ++e) o8[e] = (unsigned short)f2bf(W[(k0 + e) * HID + j]);
    int frag = ((w * 4 + g) * 32 + kb) * 2 + cf;
    *(ushortx8*)&Wt[frag * 512 + lane * 8] = o8;
}

// -------------------- persistent recurrent kernel ---------------------------
// 256 WGs x 512 threads (8 waves, 2/SIMD). grp = blockIdx%8 owns 32 batch
// rows; w = blockIdx/8 owns 32 hidden cols. Wave wv: gate = wv>>1, col-half =
// wv&1; B slice [16 cols x 1024 k] in 128 VGPRs/lane.
__global__ __launch_bounds__(512, 2)
void lstm_kernel(const int* __restrict__ x, const float* __restrict__ XW,
                 const unsigned short* __restrict__ Wt,
                 unsigned short* __restrict__ hbuf, GroupBar* __restrict__ bars) {
    __shared__ unsigned short hs[32 * 1032];   // h stage, +8 shorts pad  (66048 B)
    __shared__ float gbuf[4 * 32 * 36];        // [gate][row][col+pad]    (18432 B)
    __shared__ float xwl[384];                 // [tok][gate][32 cols]    (1536 B)

    const int tid  = threadIdx.x;
    const int grp  = blockIdx.x & 7;
    const int w    = blockIdx.x >> 3;
    const int wv   = tid >> 6;
    const int gv   = wv >> 1;                  // gate
    const int cfw  = wv & 1;                   // col-half (16 cols)
    const int lane = tid & 63;
    const int q    = lane >> 4;
    const int m    = lane & 15;

    // one-time: B fragments into registers (128 VGPRs/lane)
    bf16x8 Bf[32];
    {
        const unsigned short* wb = Wt + (size_t)((w * 4 + gv) * 32) * 2 * 512
                                      + (size_t)cfw * 512 + (size_t)lane * 8;
        #pragma unroll
        for (int kb = 0; kb < 32; ++kb)
            Bf[kb] = *(const bf16x8*)(wb + kb * 1024);
    }
    // one-time: XW slice into LDS
    if (tid < 384) {
        int tok = tid >> 7, g = (tid >> 5) & 3, jl = tid & 31;
        xwl[tid] = XW[(tok * 4 + g) * HID + w * 32 + jl];
    }
    __syncthreads();

    // elementwise ownership: thread -> row = tid>>4, cols jc2*2..+2
    const int erow = tid >> 4;
    const int jc2  = tid & 15;
    float cst[2] = {0.f, 0.f};
    GroupBar* bar = &bars[grp];

    for (int s = 0; s < T_SEQ; ++s) {
        // ---- stage h(s)[32 rows x 1024] into padded LDS ----
        const unsigned short* hp = hbuf + (size_t)(s & 1) * BATCH * HID + grp * 32 * HID;
        #pragma unroll
        for (int it = 0; it < 8; ++it) {
            int flat = it * 512 + tid;
            int row  = flat >> 7;
            int c8   = (flat & 127) << 3;
            *(uint4*)&hs[row * 1032 + c8] = *(const uint4*)&hp[row * 1024 + c8];
        }
        __syncthreads();

        // ---- GEMM: rows 0..31 x cols cfw*16.. for gate gv, B from registers ----
        floatx4 acc0 = {0.f, 0.f, 0.f, 0.f};
        floatx4 acc1 = {0.f, 0.f, 0.f, 0.f};
        const unsigned short* ap = hs + m * 1032 + q * 8;
        #pragma unroll
        for (int kb = 0; kb < 32; ++kb) {
            bf16x8 a0 = *(const bf16x8*)(ap + kb * 32);
            bf16x8 a1 = *(const bf16x8*)(ap + 16 * 1032 + kb * 32);
            acc0 = __builtin_amdgcn_mfma_f32_16x16x32_bf16(a0, Bf[kb], acc0, 0, 0, 0);
            acc1 = __builtin_amdgcn_mfma_f32_16x16x32_bf16(a1, Bf[kb], acc1, 0, 0, 0);
        }

        // ---- scatter C (col=lane&15, row=quad*4+reg) into gbuf ----
        #pragma unroll
        for (int rr = 0; rr < 4; ++rr) {
            gbuf[(gv * 32 +      q * 4 + rr) * 36 + cfw * 16 + m] = acc0[rr];
            gbuf[(gv * 32 + 16 + q * 4 + rr) * 36 + cfw * 16 + m] = acc1[rr];
        }
        __syncthreads();

        // ---- elementwise LSTM cell update, h(s+1) out ----
        {
            int tk = x[(grp * 32 + erow) * T_SEQ + s];
            const float* xb = &xwl[tk * 128];
            floatx2 ag = *(const floatx2*)&gbuf[(0 * 32 + erow) * 36 + jc2 * 2];
            floatx2 ai = *(const floatx2*)&gbuf[(1 * 32 + erow) * 36 + jc2 * 2];
            floatx2 af = *(const floatx2*)&gbuf[(2 * 32 + erow) * 36 + jc2 * 2];
            floatx2 ao = *(const floatx2*)&gbuf[(3 * 32 + erow) * 36 + jc2 * 2];
            floatx2 xg = *(const floatx2*)&xb[0 * 32 + jc2 * 2];
            floatx2 xi = *(const floatx2*)&xb[1 * 32 + jc2 * 2];
            floatx2 xf = *(const floatx2*)&xb[2 * 32 + jc2 * 2];
            floatx2 xo = *(const floatx2*)&xb[3 * 32 + jc2 * 2];
            unsigned int hv[2];
            #pragma unroll
            for (int u = 0; u < 2; ++u) {
                float g  = tanh_fast(ag[u] + xg[u]);
                float ii = sig_fast(ai[u] + xi[u]);
                float ff = sig_fast(af[u] + xf[u]);
                float oo = sig_fast(ao[u] + xo[u]);
                float cn = g * ii + cst[u] * ff;
                float h  = tanh_fast(cn) * oo;
                cst[u]   = (tk != 0) ? cn : 0.0f;   // pad = ((x+1)//2) in {0,1,1}
                hv[u]    = f2bf(h);
            }
            unsigned short* hnext = hbuf + (size_t)((s + 1) & 1) * BATCH * HID;
            *(unsigned int*)&hnext[(grp * 32 + erow) * HID + w * 32 + jc2 * 2]
                = hv[0] | (hv[1] << 16);
        }

        if (s < T_SEQ - 1) group_barrier(bar, (unsigned int)(s + 1));
        else __syncthreads();
    }
}

// -------------------- projection + log_softmax over batch dim ---------------
__global__ void proj_kernel(const unsigned short* __restrict__ h,
                            const float* __restrict__ wph, const float* __restrict__ bp,
                            float* __restrict__ out) {
    __shared__ float wl[HID * NCLS];
    __shared__ float red[256];
    int tid = threadIdx.x;      // = batch row
    for (int i = tid; i < HID * NCLS; i += 256) wl[i] = wph[i];
    __syncthreads();
    float p[NCLS];
    #pragma unroll
    for (int c2 = 0; c2 < NCLS; ++c2) p[c2] = bp[c2];
    const unsigned short* hr = h + tid * HID;
    for (int k0 = 0; k0 < HID / 8; ++k0) {
        bf16x8 hv = *(const bf16x8*)(hr + k0 * 8);
        #pragma unroll
        for (int j = 0; j < 8; ++j) {
            float hk = (float)hv[j];
            #pragma unroll
            for (int c2 = 0; c2 < NCLS; ++c2) p[c2] += hk * wl[(k0 * 8 + j) * NCLS + c2];
        }
    }
    for (int c2 = 0; c2 < NCLS; ++c2) {
        red[tid] = p[c2];
        __syncthreads();
        for (int s = 128; s > 0; s >>= 1) {
            if (tid < s) red[tid] = fmaxf(red[tid], red[tid + s]);
            __syncthreads();
        }
        float mx = red[0];
        __syncthreads();
        red[tid] = __expf(p[c2] - mx);
        __syncthreads();
        for (int s = 128; s > 0; s >>= 1) {
            if (tid < s) red[tid] += red[tid + s];
            __syncthreads();
        }
        float lse = mx + __logf(red[0]);
        __syncthreads();
        out[tid * NCLS + c2] = p[c2] - lse;
    }
}

// ----------------------------------------------------------------------------
extern "C" void kernel_launch(void* const* d_in, const int* in_sizes, int n_in,
                              void* d_out, int out_size, void* d_ws, size_t ws_size,
                              hipStream_t stream) {
    const int*   x    = (const int*)d_in[0];
    const float* emb  = (const float*)d_in[1];
    const float* wgx  = (const float*)d_in[2];
    const float* wgh  = (const float*)d_in[3];
    const float* bg_  = (const float*)d_in[4];
    const float* wix  = (const float*)d_in[5];
    const float* wih  = (const float*)d_in[6];
    const float* bi_  = (const float*)d_in[7];
    const float* wfx  = (const float*)d_in[8];
    const float* wfh  = (const float*)d_in[9];
    const float* bf_  = (const float*)d_in[10];
    const float* wox  = (const float*)d_in[11];
    const float* woh  = (const float*)d_in[12];
    const float* bo_  = (const float*)d_in[13];
    const float* wph  = (const float*)d_in[14];
    const float* bp_  = (const float*)d_in[15];
    float* out = (float*)d_out;

    char* wsp = (char*)d_ws;
    GroupBar*       bars = (GroupBar*)wsp;                                  // 4 KB
    float*          XW   = (float*)(wsp + 4096);                            // 48 KB
    unsigned short* Wt   = (unsigned short*)(wsp + 4096 + 49152);           // 8 MB
    unsigned short* hbuf = (unsigned short*)(wsp + 4096 + 49152 + 8388608); // 1 MB

    hipMemsetAsync(bars, 0, 4096, stream);
    hipMemsetAsync(hbuf, 0, BATCH * HID * sizeof(unsigned short), stream);  // h0 = 0

    prep_xw_kernel<<<48, 256, 0, stream>>>(emb, wgx, wix, wfx, wox,
                                           bg_, bi_, bf_, bo_, XW);
    prep_w_kernel<<<4096, 128, 0, stream>>>(wgh, wih, wfh, woh, Wt);

    void* args[] = { (void*)&x, (void*)&XW, (void*)&Wt, (void*)&hbuf, (void*)&bars };
    hipError_t cerr = hipLaunchCooperativeKernel((void*)lstm_kernel, dim3(256), dim3(512),
                                                 args, 0, stream);
    if (cerr != hipSuccess) {
        // Fallback: plain launch. The hand-rolled group barrier needs only
        // co-residency, which grid=256 at 1 WG/CU provides.
        lstm_kernel<<<dim3(256), dim3(512), 0, stream>>>(x, XW, Wt, hbuf, bars);
    }

    proj_kernel<<<1, 256, 0, stream>>>(hbuf, wph, bp_, out);
}

// Round 5
// 2460.572 us; speedup vs baseline: 5.2219x; 2.9114x over previous
//
#include <hip/hip_runtime.h>
#include <hip/hip_bf16.h>

#define T_SEQ 512
#define BATCH 256
#define HID   1024
#define EMBD  256
#define NCLS  10

typedef __bf16 bf16x8 __attribute__((ext_vector_type(8)));
typedef float  floatx4 __attribute__((ext_vector_type(4)));
typedef float  floatx2 __attribute__((ext_vector_type(2)));
typedef unsigned short ushortx8 __attribute__((ext_vector_type(8)));

__device__ __forceinline__ unsigned int f2bf(float f) {
    unsigned int u = __builtin_bit_cast(unsigned int, f);
    u += 0x7fffu + ((u >> 16) & 1u);
    return u >> 16;
}
__device__ __forceinline__ float sig_fast(float x) {
    return __builtin_amdgcn_rcpf(1.0f + __expf(-x));
}
__device__ __forceinline__ float tanh_fast(float x) {
    return 1.0f - 2.0f * __builtin_amdgcn_rcpf(1.0f + __expf(2.0f * x));
}

// -------------------- prep: XW[tok][gate][n] = emb[tok] @ Wx_gate + b_gate ---
__global__ void prep_xw_kernel(const float* __restrict__ emb,
                               const float* __restrict__ wgx, const float* __restrict__ wix,
                               const float* __restrict__ wfx, const float* __restrict__ wox,
                               const float* __restrict__ bg,  const float* __restrict__ bi,
                               const float* __restrict__ bf,  const float* __restrict__ bo,
                               float* __restrict__ XW) {
    int gid = blockIdx.x * blockDim.x + threadIdx.x;     // 3*4*1024 = 12288
    if (gid >= 3 * 4 * HID) return;
    int tok  = gid >> 12;
    int gate = (gid >> 10) & 3;
    int n    = gid & 1023;
    const float* W = gate == 0 ? wgx : gate == 1 ? wix : gate == 2 ? wfx : wox;
    const float* B = gate == 0 ? bg  : gate == 1 ? bi  : gate == 2 ? bf  : bo;
    float acc = B[n];
    const float* e = emb + tok * EMBD;
    for (int k = 0; k < EMBD; ++k) acc += e[k] * W[k * HID + n];
    XW[gid] = acc;
}

// ---- prep: Wt in MFMA B-fragment order ----
// frag_id(w,g,kb,cf) = ((w*4+g)*32+kb)*2+cf ; Wt[frag_id*512 + lane*8 + e]
//   = bf16( W_g[k = kb*32 + (lane>>4)*8 + e][j = w*32 + cf*16 + (lane&15)] )
__global__ void prep_w_kernel(const float* __restrict__ wgh, const float* __restrict__ wih,
                              const float* __restrict__ wfh, const float* __restrict__ woh,
                              unsigned short* __restrict__ Wt) {
    int bid = blockIdx.x;                 // 4096 = g(4) x kb(32) x w(32)
    int g   = bid >> 10;
    int kb  = (bid >> 5) & 31;
    int w   = bid & 31;
    const float* W = g == 0 ? wgh : g == 1 ? wih : g == 2 ? wfh : woh;
    int t    = threadIdx.x;               // 128
    int cf   = t >> 6;
    int lane = t & 63;
    int q    = lane >> 4;
    int n    = lane & 15;
    int j    = w * 32 + cf * 16 + n;
    int k0   = kb * 32 + q * 8;
    ushortx8 o8;
    #pragma unroll
    for (int e = 0; e < 8; ++e) o8[e] = (unsigned short)f2bf(W[(k0 + e) * HID + j]);
    int frag = ((w * 4 + g) * 32 + kb) * 2 + cf;
    *(ushortx8*)&Wt[frag * 512 + lane * 8] = o8;
}

// -------------------- persistent recurrent kernel ---------------------------
// 256 WGs x 512 threads (8 waves, 2/SIMD). grp = blockIdx%8 owns 32 batch
// rows; w = blockIdx/8 owns 32 hidden cols. Wave wv: gate = wv>>1, col-half =
// wv&1; B slice [16 cols x 1024 k] in 128 regs/lane (AGPR-backed).
//
// Cross-WG h exchange: relaxed agent-scope atomics only (sc0|sc1 -> LLC
// coherence point). NO __threadfence => no buffer_wbl2/inv L2-flush storms
// (R4's WRITE_SIZE=266MB == 512 steps x 512KB h forced to HBM by fences).
__global__ __launch_bounds__(512, 2)
void lstm_kernel(const int* __restrict__ x, const float* __restrict__ XW,
                 const unsigned short* __restrict__ Wt,
                 unsigned int* __restrict__ hbuf32, int* __restrict__ flags) {
    __shared__ unsigned short hs[32 * 1032];   // h stage, +8 shorts pad  (66048 B)
    __shared__ float gbuf[4 * 32 * 36];        // [gate][row][col+pad]    (18432 B)
    __shared__ float xwl[384];                 // [tok][gate][32 cols]    (1536 B)

    const int tid  = threadIdx.x;
    const int grp  = blockIdx.x & 7;
    const int w    = blockIdx.x >> 3;
    const int wv   = tid >> 6;
    const int gv   = wv >> 1;                  // gate
    const int cfw  = wv & 1;                   // col-half (16 cols)
    const int lane = tid & 63;
    const int q    = lane >> 4;
    const int m    = lane & 15;

    // one-time: B fragments into registers (128 regs/lane)
    bf16x8 Bf[32];
    {
        const unsigned short* wb = Wt + (size_t)((w * 4 + gv) * 32) * 2 * 512
                                      + (size_t)cfw * 512 + (size_t)lane * 8;
        #pragma unroll
        for (int kb = 0; kb < 32; ++kb)
            Bf[kb] = *(const bf16x8*)(wb + kb * 1024);
    }
    // one-time: XW slice into LDS
    if (tid < 384) {
        int tok = tid >> 7, g = (tid >> 5) & 3, jl = tid & 31;
        xwl[tid] = XW[(tok * 4 + g) * HID + w * 32 + jl];
    }
    __syncthreads();

    // elementwise ownership: thread -> row = tid>>4, cols jc2*2..+2
    const int erow = tid >> 4;
    const int jc2  = tid & 15;
    float cst[2] = {0.f, 0.f};
    unsigned int* hs32 = (unsigned int*)hs;

    for (int s = 0; s < T_SEQ; ++s) {
        // ---- wait for h(s) from all 32 group members (flags start at 0) ----
        if (s > 0) {
            if (wv == 0) {
                const int fidx = grp * 32 + (lane & 31);
                while (__hip_atomic_load(&flags[fidx], __ATOMIC_RELAXED,
                                         __HIP_MEMORY_SCOPE_AGENT) < s) {
                    __builtin_amdgcn_s_sleep(1);
                }
            }
            __syncthreads();
        }

        // ---- stage h(s)[32 rows x 512 dwords] into padded LDS (LLC loads) ----
        const unsigned int* hp32 = hbuf32 + (size_t)(s & 1) * (BATCH * HID / 2)
                                          + grp * 32 * 512;
        #pragma unroll
        for (int half = 0; half < 2; ++half) {
            unsigned int tmp[16];
            #pragma unroll
            for (int it = 0; it < 16; ++it) {
                int row = half * 16 + it;
                tmp[it] = __hip_atomic_load(&hp32[row * 512 + tid],
                                            __ATOMIC_RELAXED, __HIP_MEMORY_SCOPE_AGENT);
            }
            #pragma unroll
            for (int it = 0; it < 16; ++it) {
                int row = half * 16 + it;
                hs32[row * 516 + tid] = tmp[it];
            }
        }
        __syncthreads();

        // ---- GEMM: rows 0..31 x cols cfw*16.. for gate gv, B from registers ----
        floatx4 acc0 = {0.f, 0.f, 0.f, 0.f};
        floatx4 acc1 = {0.f, 0.f, 0.f, 0.f};
        const unsigned short* ap = hs + m * 1032 + q * 8;
        #pragma unroll
        for (int kb = 0; kb < 32; ++kb) {
            bf16x8 a0 = *(const bf16x8*)(ap + kb * 32);
            bf16x8 a1 = *(const bf16x8*)(ap + 16 * 1032 + kb * 32);
            acc0 = __builtin_amdgcn_mfma_f32_16x16x32_bf16(a0, Bf[kb], acc0, 0, 0, 0);
            acc1 = __builtin_amdgcn_mfma_f32_16x16x32_bf16(a1, Bf[kb], acc1, 0, 0, 0);
        }

        // ---- scatter C (col=lane&15, row=quad*4+reg) into gbuf ----
        #pragma unroll
        for (int rr = 0; rr < 4; ++rr) {
            gbuf[(gv * 32 +      q * 4 + rr) * 36 + cfw * 16 + m] = acc0[rr];
            gbuf[(gv * 32 + 16 + q * 4 + rr) * 36 + cfw * 16 + m] = acc1[rr];
        }
        __syncthreads();

        // ---- elementwise LSTM cell update, h(s+1) out (LLC write-through) ----
        {
            int tk = x[(grp * 32 + erow) * T_SEQ + s];
            const float* xb = &xwl[tk * 128];
            floatx2 ag = *(const floatx2*)&gbuf[(0 * 32 + erow) * 36 + jc2 * 2];
            floatx2 ai = *(const floatx2*)&gbuf[(1 * 32 + erow) * 36 + jc2 * 2];
            floatx2 af = *(const floatx2*)&gbuf[(2 * 32 + erow) * 36 + jc2 * 2];
            floatx2 ao = *(const floatx2*)&gbuf[(3 * 32 + erow) * 36 + jc2 * 2];
            floatx2 xg = *(const floatx2*)&xb[0 * 32 + jc2 * 2];
            floatx2 xi = *(const floatx2*)&xb[1 * 32 + jc2 * 2];
            floatx2 xf = *(const floatx2*)&xb[2 * 32 + jc2 * 2];
            floatx2 xo = *(const floatx2*)&xb[3 * 32 + jc2 * 2];
            unsigned int hv[2];
            #pragma unroll
            for (int u = 0; u < 2; ++u) {
                float g  = tanh_fast(ag[u] + xg[u]);
                float ii = sig_fast(ai[u] + xi[u]);
                float ff = sig_fast(af[u] + xf[u]);
                float oo = sig_fast(ao[u] + xo[u]);
                float cn = g * ii + cst[u] * ff;
                float h  = tanh_fast(cn) * oo;
                cst[u]   = (tk != 0) ? cn : 0.0f;   // pad = ((x+1)//2) in {0,1,1}
                hv[u]    = f2bf(h);
            }
            unsigned int* hnext = hbuf32 + (size_t)((s + 1) & 1) * (BATCH * HID / 2);
            __hip_atomic_store(&hnext[((grp * 32 + erow) * HID + w * 32 + jc2 * 2) >> 1],
                               hv[0] | (hv[1] << 16),
                               __ATOMIC_RELAXED, __HIP_MEMORY_SCOPE_AGENT);
        }
        // syncthreads drains each wave's vmcnt before s_barrier => on exit, all
        // h stores of this WG have completed at the LLC coherence point.
        __syncthreads();

        if (s < T_SEQ - 1 && tid == 0) {
            __hip_atomic_store(&flags[grp * 32 + w], s + 1,
                               __ATOMIC_RELAXED, __HIP_MEMORY_SCOPE_AGENT);
        }
    }
}

// -------------------- projection + log_softmax over batch dim ---------------
__global__ void proj_kernel(const unsigned short* __restrict__ h,
                            const float* __restrict__ wph, const float* __restrict__ bp,
                            float* __restrict__ out) {
    __shared__ float wl[HID * NCLS];
    __shared__ float red[256];
    int tid = threadIdx.x;      // = batch row
    for (int i = tid; i < HID * NCLS; i += 256) wl[i] = wph[i];
    __syncthreads();
    float p[NCLS];
    #pragma unroll
    for (int c2 = 0; c2 < NCLS; ++c2) p[c2] = bp[c2];
    const unsigned short* hr = h + tid * HID;
    for (int k0 = 0; k0 < HID / 8; ++k0) {
        bf16x8 hv = *(const bf16x8*)(hr + k0 * 8);
        #pragma unroll
        for (int j = 0; j < 8; ++j) {
            float hk = (float)hv[j];
            #pragma unroll
            for (int c2 = 0; c2 < NCLS; ++c2) p[c2] += hk * wl[(k0 * 8 + j) * NCLS + c2];
        }
    }
    for (int c2 = 0; c2 < NCLS; ++c2) {
        red[tid] = p[c2];
        __syncthreads();
        for (int s = 128; s > 0; s >>= 1) {
            if (tid < s) red[tid] = fmaxf(red[tid], red[tid + s]);
            __syncthreads();
        }
        float mx = red[0];
        __syncthreads();
        red[tid] = __expf(p[c2] - mx);
        __syncthreads();
        for (int s = 128; s > 0; s >>= 1) {
            if (tid < s) red[tid] += red[tid + s];
            __syncthreads();
        }
        float lse = mx + __logf(red[0]);
        __syncthreads();
        out[tid * NCLS + c2] = p[c2] - lse;
    }
}

// ----------------------------------------------------------------------------
extern "C" void kernel_launch(void* const* d_in, const int* in_sizes, int n_in,
                              void* d_out, int out_size, void* d_ws, size_t ws_size,
                              hipStream_t stream) {
    const int*   x    = (const int*)d_in[0];
    const float* emb  = (const float*)d_in[1];
    const float* wgx  = (const float*)d_in[2];
    const float* wgh  = (const float*)d_in[3];
    const float* bg_  = (const float*)d_in[4];
    const float* wix  = (const float*)d_in[5];
    const float* wih  = (const float*)d_in[6];
    const float* bi_  = (const float*)d_in[7];
    const float* wfx  = (const float*)d_in[8];
    const float* wfh  = (const float*)d_in[9];
    const float* bf_  = (const float*)d_in[10];
    const float* wox  = (const float*)d_in[11];
    const float* woh  = (const float*)d_in[12];
    const float* bo_  = (const float*)d_in[13];
    const float* wph  = (const float*)d_in[14];
    const float* bp_  = (const float*)d_in[15];
    float* out = (float*)d_out;

    char* wsp = (char*)d_ws;
    int*            flags = (int*)wsp;                                      // 4 KB
    float*          XW    = (float*)(wsp + 4096);                           // 48 KB
    unsigned short* Wt    = (unsigned short*)(wsp + 4096 + 49152);          // 8 MB
    unsigned int*   hbuf32= (unsigned int*)(wsp + 4096 + 49152 + 8388608);  // 1 MB

    hipMemsetAsync(flags, 0, 4096, stream);
    hipMemsetAsync(hbuf32, 0, BATCH * HID * sizeof(unsigned short), stream); // h0 = 0

    prep_xw_kernel<<<48, 256, 0, stream>>>(emb, wgx, wix, wfx, wox,
                                           bg_, bi_, bf_, bo_, XW);
    prep_w_kernel<<<4096, 128, 0, stream>>>(wgh, wih, wfh, woh, Wt);

    void* args[] = { (void*)&x, (void*)&XW, (void*)&Wt, (void*)&hbuf32, (void*)&flags };
    hipError_t cerr = hipLaunchCooperativeKernel((void*)lstm_kernel, dim3(256), dim3(512),
                                                 args, 0, stream);
    if (cerr != hipSuccess) {
        // Fallback: plain launch. The flag protocol needs only co-residency,
        // which grid=256 at 1 WG/CU provides.
        lstm_kernel<<<dim3(256), dim3(512), 0, stream>>>(x, XW, Wt, hbuf32, flags);
    }

    proj_kernel<<<1, 256, 0, stream>>>((const unsigned short*)hbuf32, wph, bp_, out);
}

// Round 6
// 2140.934 us; speedup vs baseline: 6.0015x; 1.1493x over previous
//
#include <hip/hip_runtime.h>
#include <hip/hip_bf16.h>

#define T_SEQ 512
#define BATCH 256
#define HID   1024
#define EMBD  256
#define NCLS  10

typedef __bf16 bf16x8 __attribute__((ext_vector_type(8)));
typedef float  floatx16 __attribute__((ext_vector_type(16)));
typedef float  floatx2 __attribute__((ext_vector_type(2)));
typedef unsigned short ushortx8 __attribute__((ext_vector_type(8)));

__device__ __forceinline__ unsigned int f2bf(float f) {
    unsigned int u = __builtin_bit_cast(unsigned int, f);
    u += 0x7fffu + ((u >> 16) & 1u);
    return u >> 16;
}
__device__ __forceinline__ float sig_fast(float x) {
    return __builtin_amdgcn_rcpf(1.0f + __expf(-x));
}
__device__ __forceinline__ float tanh_fast(float x) {
    return 1.0f - 2.0f * __builtin_amdgcn_rcpf(1.0f + __expf(2.0f * x));
}

// -------------------- prep: XW[tok][gate][n] = emb[tok] @ Wx_gate + b_gate ---
__global__ void prep_xw_kernel(const float* __restrict__ emb,
                               const float* __restrict__ wgx, const float* __restrict__ wix,
                               const float* __restrict__ wfx, const float* __restrict__ wox,
                               const float* __restrict__ bg,  const float* __restrict__ bi,
                               const float* __restrict__ bf,  const float* __restrict__ bo,
                               float* __restrict__ XW) {
    int gid = blockIdx.x * blockDim.x + threadIdx.x;     // 3*4*1024 = 12288
    if (gid >= 3 * 4 * HID) return;
    int tok  = gid >> 12;
    int gate = (gid >> 10) & 3;
    int n    = gid & 1023;
    const float* W = gate == 0 ? wgx : gate == 1 ? wix : gate == 2 ? wfx : wox;
    const float* B = gate == 0 ? bg  : gate == 1 ? bi  : gate == 2 ? bf  : bo;
    float acc = B[n];
    const float* e = emb + tok * EMBD;
    for (int k = 0; k < EMBD; ++k) acc += e[k] * W[k * HID + n];
    XW[gid] = acc;
}

// ---- prep: Wt in 32x32x16 MFMA B-fragment order ----
// frag = ((w*4+g)*2+kh)*32 + i ; Wt[frag*512 + lane*8 + e]
//   = bf16( W_g[k = kh*512 + i*16 + (lane>>5)*8 + e][j = w*32 + (lane&31)] )
__global__ void prep_w_kernel(const float* __restrict__ wgh, const float* __restrict__ wih,
                              const float* __restrict__ wfh, const float* __restrict__ woh,
                              unsigned short* __restrict__ Wt) {
    int bid = blockIdx.x;                 // 8192 = g(4) x kh(2) x i(32) x w(32)
    int w   = bid & 31;
    int i   = (bid >> 5) & 31;
    int kh  = (bid >> 10) & 1;
    int g   = bid >> 11;
    const float* W = g == 0 ? wgh : g == 1 ? wih : g == 2 ? wfh : woh;
    int lane = threadIdx.x;               // 64
    int j    = w * 32 + (lane & 31);
    int k0   = kh * 512 + i * 16 + (lane >> 5) * 8;
    ushortx8 o8;
    #pragma unroll
    for (int e = 0; e < 8; ++e) o8[e] = (unsigned short)f2bf(W[(k0 + e) * HID + j]);
    int frag = ((w * 4 + g) * 2 + kh) * 32 + i;
    *(ushortx8*)&Wt[frag * 512 + lane * 8] = o8;
}

// -------------------- persistent recurrent kernel ---------------------------
// 256 WGs x 512 threads. grp = blockIdx%8 owns 32 batch rows; w = blockIdx/8
// owns 32 hidden cols. Wave wv: gate = wv>>1, K-half kh = wv&1. Each wave
// computes the gate's full 32x32 tile over its K=512 slice via
// mfma_f32_32x32x16_bf16 (A-read 32KB/wave vs 64KB for col-split: LDS
// read traffic halved). kh partials summed in the elementwise phase.
// Cross-WG h exchange: relaxed agent-scope atomics only (R5-proven).
__global__ __launch_bounds__(512, 2)
void lstm_kernel(const int* __restrict__ x, const float* __restrict__ XW,
                 const unsigned short* __restrict__ Wt,
                 unsigned int* __restrict__ hbuf32, int* __restrict__ flags) {
    __shared__ unsigned short hs[32 * 1032];      // h stage, +8 shorts pad (66048 B)
    __shared__ float gbuf[8 * 32 * 36];           // [gate][kh][row][col+pad] (36864 B)
    __shared__ float xwl[384];                    // [tok][gate][32 cols]     (1536 B)
    __shared__ unsigned char xtok[32 * 512];      // tokens, byte-packed      (16384 B)

    const int tid  = threadIdx.x;
    const int grp  = blockIdx.x & 7;
    const int w    = blockIdx.x >> 3;
    const int wv   = tid >> 6;
    const int gv   = wv >> 1;                  // gate
    const int kh   = wv & 1;                   // K-half
    const int lane = tid & 63;
    const int m32  = lane & 31;
    const int hv5  = lane >> 5;

    // one-time: B fragments into registers (128 regs/lane, AGPR-backed)
    bf16x8 Bf[32];
    {
        const unsigned short* wb = Wt + (size_t)(((w * 4 + gv) * 2 + kh) * 32) * 512
                                      + (size_t)lane * 8;
        #pragma unroll
        for (int i = 0; i < 32; ++i)
            Bf[i] = *(const bf16x8*)(wb + i * 512);
    }
    // one-time: XW slice into LDS
    if (tid < 384) {
        int tok = tid >> 7, g = (tid >> 5) & 3, jl = tid & 31;
        xwl[tid] = XW[(tok * 4 + g) * HID + w * 32 + jl];
    }
    // one-time: token table into LDS (byte-packed)
    #pragma unroll
    for (int it = 0; it < 32; ++it) {
        int flat = it * 512 + tid;                 // 16384 tokens
        int row  = flat >> 9;
        int col  = flat & 511;
        xtok[flat] = (unsigned char)x[(grp * 32 + row) * T_SEQ + col];
    }
    __syncthreads();

    // elementwise ownership: thread -> row = tid>>4, cols jc2*2..+2
    const int erow = tid >> 4;
    const int jc2  = tid & 15;
    float cst[2] = {0.f, 0.f};
    unsigned long long* hs64 = (unsigned long long*)hs;

    for (int s = 0; s < T_SEQ; ++s) {
        // ---- wait for h(s) from all 32 group members (flags start at 0) ----
        if (s > 0) {
            if (wv == 0) {
                const int fidx = grp * 32 + (lane & 31);
                while (__hip_atomic_load(&flags[fidx], __ATOMIC_RELAXED,
                                         __HIP_MEMORY_SCOPE_AGENT) < s) {
                    __builtin_amdgcn_s_sleep(1);
                }
            }
            __syncthreads();
        }

        // ---- stage h(s)[32 rows x 256 qwords] into padded LDS (LLC loads) ----
        const unsigned long long* hp64 = (const unsigned long long*)
            (hbuf32 + (size_t)(s & 1) * (BATCH * HID / 2)) + (size_t)grp * 32 * 256;
        {
            unsigned long long tmp[16];
            #pragma unroll
            for (int it = 0; it < 16; ++it) {
                int flat = it * 512 + tid;         // 8192 qwords
                int row  = flat >> 8;
                int qc   = flat & 255;
                tmp[it] = __hip_atomic_load(&hp64[row * 256 + qc],
                                            __ATOMIC_RELAXED, __HIP_MEMORY_SCOPE_AGENT);
            }
            #pragma unroll
            for (int it = 0; it < 16; ++it) {
                int flat = it * 512 + tid;
                int row  = flat >> 8;
                int qc   = flat & 255;
                hs64[row * 258 + qc] = tmp[it];
            }
        }
        __syncthreads();

        // ---- GEMM: 32x32 tile for gate gv over K-half kh, B from registers ----
        floatx16 acc = {0.f,0.f,0.f,0.f,0.f,0.f,0.f,0.f,0.f,0.f,0.f,0.f,0.f,0.f,0.f,0.f};
        const unsigned short* ap = hs + m32 * 1032 + kh * 512 + hv5 * 8;
        #pragma unroll
        for (int i = 0; i < 32; ++i) {
            bf16x8 a = *(const bf16x8*)(ap + i * 16);
            acc = __builtin_amdgcn_mfma_f32_32x32x16_bf16(a, Bf[i], acc, 0, 0, 0);
        }

        // ---- scatter C (col=lane&31, row=(reg&3)+8*(reg>>2)+4*(lane>>5)) ----
        {
            float* gb = &gbuf[(size_t)(gv * 2 + kh) * 32 * 36];
            #pragma unroll
            for (int reg = 0; reg < 16; ++reg) {
                int row = (reg & 3) + 8 * (reg >> 2) + 4 * hv5;
                gb[row * 36 + m32] = acc[reg];
            }
        }
        __syncthreads();

        // ---- elementwise LSTM cell update, h(s+1) out (LLC write-through) ----
        {
            int tk = xtok[erow * 512 + s];
            const float* xb = &xwl[tk * 128];
            const int go = erow * 36 + jc2 * 2;
            floatx2 ag = *(const floatx2*)&gbuf[0 * 32 * 36 + go]
                       + *(const floatx2*)&gbuf[1 * 32 * 36 + go];
            floatx2 ai = *(const floatx2*)&gbuf[2 * 32 * 36 + go]
                       + *(const floatx2*)&gbuf[3 * 32 * 36 + go];
            floatx2 af = *(const floatx2*)&gbuf[4 * 32 * 36 + go]
                       + *(const floatx2*)&gbuf[5 * 32 * 36 + go];
            floatx2 ao = *(const floatx2*)&gbuf[6 * 32 * 36 + go]
                       + *(const floatx2*)&gbuf[7 * 32 * 36 + go];
            floatx2 xg = *(const floatx2*)&xb[0 * 32 + jc2 * 2];
            floatx2 xi = *(const floatx2*)&xb[1 * 32 + jc2 * 2];
            floatx2 xf = *(const floatx2*)&xb[2 * 32 + jc2 * 2];
            floatx2 xo = *(const floatx2*)&xb[3 * 32 + jc2 * 2];
            unsigned int hvv[2];
            #pragma unroll
            for (int u = 0; u < 2; ++u) {
                float g  = tanh_fast(ag[u] + xg[u]);
                float ii = sig_fast(ai[u] + xi[u]);
                float ff = sig_fast(af[u] + xf[u]);
                float oo = sig_fast(ao[u] + xo[u]);
                float cn = g * ii + cst[u] * ff;
                float h  = tanh_fast(cn) * oo;
                cst[u]   = (tk != 0) ? cn : 0.0f;   // pad = ((x+1)//2) in {0,1,1}
                hvv[u]   = f2bf(h);
            }
            unsigned int* hnext = hbuf32 + (size_t)((s + 1) & 1) * (BATCH * HID / 2);
            __hip_atomic_store(&hnext[((grp * 32 + erow) * HID + w * 32 + jc2 * 2) >> 1],
                               hvv[0] | (hvv[1] << 16),
                               __ATOMIC_RELAXED, __HIP_MEMORY_SCOPE_AGENT);
        }
        // syncthreads drains each wave's vmcnt before s_barrier => on exit, all
        // h stores of this WG have completed at the LLC coherence point.
        __syncthreads();

        if (s < T_SEQ - 1 && tid == 0) {
            __hip_atomic_store(&flags[grp * 32 + w], s + 1,
                               __ATOMIC_RELAXED, __HIP_MEMORY_SCOPE_AGENT);
        }
    }
}

// -------------------- projection + log_softmax over batch dim ---------------
__global__ void proj_kernel(const unsigned short* __restrict__ h,
                            const float* __restrict__ wph, const float* __restrict__ bp,
                            float* __restrict__ out) {
    __shared__ float wl[HID * NCLS];
    __shared__ float red[256];
    int tid = threadIdx.x;      // = batch row
    for (int i = tid; i < HID * NCLS; i += 256) wl[i] = wph[i];
    __syncthreads();
    float p[NCLS];
    #pragma unroll
    for (int c2 = 0; c2 < NCLS; ++c2) p[c2] = bp[c2];
    const unsigned short* hr = h + tid * HID;
    for (int k0 = 0; k0 < HID / 8; ++k0) {
        bf16x8 hv = *(const bf16x8*)(hr + k0 * 8);
        #pragma unroll
        for (int j = 0; j < 8; ++j) {
            float hk = (float)hv[j];
            #pragma unroll
            for (int c2 = 0; c2 < NCLS; ++c2) p[c2] += hk * wl[(k0 * 8 + j) * NCLS + c2];
        }
    }
    for (int c2 = 0; c2 < NCLS; ++c2) {
        red[tid] = p[c2];
        __syncthreads();
        for (int s = 128; s > 0; s >>= 1) {
            if (tid < s) red[tid] = fmaxf(red[tid], red[tid + s]);
            __syncthreads();
        }
        float mx = red[0];
        __syncthreads();
        red[tid] = __expf(p[c2] - mx);
        __syncthreads();
        for (int s = 128; s > 0; s >>= 1) {
            if (tid < s) red[tid] += red[tid + s];
            __syncthreads();
        }
        float lse = mx + __logf(red[0]);
        __syncthreads();
        out[tid * NCLS + c2] = p[c2] - lse;
    }
}

// ----------------------------------------------------------------------------
extern "C" void kernel_launch(void* const* d_in, const int* in_sizes, int n_in,
                              void* d_out, int out_size, void* d_ws, size_t ws_size,
                              hipStream_t stream) {
    const int*   x    = (const int*)d_in[0];
    const float* emb  = (const float*)d_in[1];
    const float* wgx  = (const float*)d_in[2];
    const float* wgh  = (const float*)d_in[3];
    const float* bg_  = (const float*)d_in[4];
    const float* wix  = (const float*)d_in[5];
    const float* wih  = (const float*)d_in[6];
    const float* bi_  = (const float*)d_in[7];
    const float* wfx  = (const float*)d_in[8];
    const float* wfh  = (const float*)d_in[9];
    const float* bf_  = (const float*)d_in[10];
    const float* wox  = (const float*)d_in[11];
    const float* woh  = (const float*)d_in[12];
    const float* bo_  = (const float*)d_in[13];
    const float* wph  = (const float*)d_in[14];
    const float* bp_  = (const float*)d_in[15];
    float* out = (float*)d_out;

    char* wsp = (char*)d_ws;
    int*            flags = (int*)wsp;                                      // 4 KB
    float*          XW    = (float*)(wsp + 4096);                           // 48 KB
    unsigned short* Wt    = (unsigned short*)(wsp + 4096 + 49152);          // 8 MB
    unsigned int*   hbuf32= (unsigned int*)(wsp + 4096 + 49152 + 8388608);  // 1 MB

    hipMemsetAsync(flags, 0, 4096, stream);
    hipMemsetAsync(hbuf32, 0, BATCH * HID * sizeof(unsigned short), stream); // h0 = 0

    prep_xw_kernel<<<48, 256, 0, stream>>>(emb, wgx, wix, wfx, wox,
                                           bg_, bi_, bf_, bo_, XW);
    prep_w_kernel<<<8192, 64, 0, stream>>>(wgh, wih, wfh, woh, Wt);

    void* args[] = { (void*)&x, (void*)&XW, (void*)&Wt, (void*)&hbuf32, (void*)&flags };
    hipError_t cerr = hipLaunchCooperativeKernel((void*)lstm_kernel, dim3(256), dim3(512),
                                                 args, 0, stream);
    if (cerr != hipSuccess) {
        // Fallback: plain launch. The flag protocol needs only co-residency,
        // which grid=256 at 1 WG/CU provides.
        lstm_kernel<<<dim3(256), dim3(512), 0, stream>>>(x, XW, Wt, hbuf32, flags);
    }

    proj_kernel<<<1, 256, 0, stream>>>((const unsigned short*)hbuf32, wph, bp_, out);
}

// Round 7
// 1760.120 us; speedup vs baseline: 7.2999x; 1.2164x over previous
//
#include <hip/hip_runtime.h>
#include <hip/hip_bf16.h>

#define T_SEQ 512
#define BATCH 256
#define HID   1024
#define EMBD  256
#define NCLS  10

typedef __bf16 bf16x8 __attribute__((ext_vector_type(8)));
typedef float  floatx16 __attribute__((ext_vector_type(16)));
typedef float  floatx2 __attribute__((ext_vector_type(2)));
typedef unsigned short ushortx8 __attribute__((ext_vector_type(8)));

__device__ __forceinline__ unsigned int f2bf(float f) {
    unsigned int u = __builtin_bit_cast(unsigned int, f);
    u += 0x7fffu + ((u >> 16) & 1u);
    return u >> 16;
}
__device__ __forceinline__ float sig_fast(float x) {
    return __builtin_amdgcn_rcpf(1.0f + __expf(-x));
}
__device__ __forceinline__ float tanh_fast(float x) {
    return 1.0f - 2.0f * __builtin_amdgcn_rcpf(1.0f + __expf(2.0f * x));
}

// -------------------- prep: XW[tok][gate][n] = emb[tok] @ Wx_gate + b_gate ---
__global__ void prep_xw_kernel(const float* __restrict__ emb,
                               const float* __restrict__ wgx, const float* __restrict__ wix,
                               const float* __restrict__ wfx, const float* __restrict__ wox,
                               const float* __restrict__ bg,  const float* __restrict__ bi,
                               const float* __restrict__ bf,  const float* __restrict__ bo,
                               float* __restrict__ XW) {
    int gid = blockIdx.x * blockDim.x + threadIdx.x;     // 3*4*1024 = 12288
    if (gid >= 3 * 4 * HID) return;
    int tok  = gid >> 12;
    int gate = (gid >> 10) & 3;
    int n    = gid & 1023;
    const float* W = gate == 0 ? wgx : gate == 1 ? wix : gate == 2 ? wfx : wox;
    const float* B = gate == 0 ? bg  : gate == 1 ? bi  : gate == 2 ? bf  : bo;
    float acc = B[n];
    const float* e = emb + tok * EMBD;
    for (int k = 0; k < EMBD; ++k) acc += e[k] * W[k * HID + n];
    XW[gid] = acc;
}

// ---- prep: Wt in 32x32x16 MFMA B-fragment order ----
// frag = ((w*4+g)*2+kh)*32 + i ; Wt[frag*512 + lane*8 + e]
//   = bf16( W_g[k = kh*512 + i*16 + (lane>>5)*8 + e][j = w*32 + (lane&31)] )
__global__ void prep_w_kernel(const float* __restrict__ wgh, const float* __restrict__ wih,
                              const float* __restrict__ wfh, const float* __restrict__ woh,
                              unsigned short* __restrict__ Wt) {
    int bid = blockIdx.x;                 // 8192 = g(4) x kh(2) x i(32) x w(32)
    int w   = bid & 31;
    int i   = (bid >> 5) & 31;
    int kh  = (bid >> 10) & 1;
    int g   = bid >> 11;
    const float* W = g == 0 ? wgh : g == 1 ? wih : g == 2 ? wfh : woh;
    int lane = threadIdx.x;               // 64
    int j    = w * 32 + (lane & 31);
    int k0   = kh * 512 + i * 16 + (lane >> 5) * 8;
    ushortx8 o8;
    #pragma unroll
    for (int e = 0; e < 8; ++e) o8[e] = (unsigned short)f2bf(W[(k0 + e) * HID + j]);
    int frag = ((w * 4 + g) * 2 + kh) * 32 + i;
    *(ushortx8*)&Wt[frag * 512 + lane * 8] = o8;
}

// -------------------- persistent recurrent kernel ---------------------------
// 256 WGs x 512 threads. grp = blockIdx%8 owns 32 batch rows; w = blockIdx/8
// owns 32 hidden cols. Wave wv: gate = wv>>1, K-half kh = wv&1 (R6-proven
// 32x32x16 MFMA structure).
//
// h/flag exchange (R7): agent-scope stores on gfx950 are WRITE-THROUGH to the
// LLC (R6 evidence: WRITE_SIZE == 512 steps x 512 KB exactly), putting a ~1000
// cyc fabric RTT on every step's store->flag->spin critical path. Agent LOADS
// are sc0-only and hit the XCD-local L2 (FETCH_SIZE 164 MB, not 8.4 GB).
// So: when all 32 group members verify (via HW_REG_XCC_ID, system-scope
// exchange) that they share an XCD, switch stores to plain write-back-L2
// stores (workgroup-scope atomic stores) -- producer and consumer share that
// L2, loads keep bypassing L1 (agent sc0). Else fall back to system-scope
// exchange (placement-independent correctness, G16).
__global__ __launch_bounds__(512, 2)
void lstm_kernel(const int* __restrict__ x, const float* __restrict__ XW,
                 const unsigned short* __restrict__ Wt,
                 unsigned int* __restrict__ hbuf32, int* __restrict__ flags,
                 int* __restrict__ xflag) {
    __shared__ unsigned short hs[32 * 1032];      // h stage, +8 shorts pad (66048 B)
    __shared__ float gbuf[8 * 32 * 36];           // [gate][kh][row][col+pad] (36864 B)
    __shared__ float xwl[384];                    // [tok][gate][32 cols]     (1536 B)
    __shared__ unsigned char xtok[32 * 512];      // tokens, byte-packed      (16384 B)
    __shared__ int use_local_sh;

    const int tid  = threadIdx.x;
    const int grp  = blockIdx.x & 7;
    const int w    = blockIdx.x >> 3;
    const int wv   = tid >> 6;
    const int gv   = wv >> 1;                  // gate
    const int kh   = wv & 1;                   // K-half
    const int lane = tid & 63;
    const int m32  = lane & 31;
    const int hv5  = lane >> 5;

    // ---- XCD-locality check (one-time, system-scope => placement-safe) ----
    {
        int xcc = 0;
        asm volatile("s_getreg_b32 %0, hwreg(HW_REG_XCC_ID)" : "=s"(xcc));
        if (tid == 0) {
            __hip_atomic_store(&xflag[grp * 32 + w], xcc + 1, __ATOMIC_RELAXED,
                               __HIP_MEMORY_SCOPE_SYSTEM);
        }
        if (wv == 0) {
            int v;
            for (;;) {
                v = __hip_atomic_load(&xflag[grp * 32 + (lane & 31)], __ATOMIC_RELAXED,
                                      __HIP_MEMORY_SCOPE_SYSTEM);
                if (__all(v != 0)) break;
                __builtin_amdgcn_s_sleep(2);
            }
            int v0 = __shfl(v, 0, 64);
            if (lane == 0) use_local_sh = __all(v == v0) ? 1 : 0;
        }
    }

    // one-time: B fragments into registers (128 regs/lane, AGPR-backed)
    bf16x8 Bf[32];
    {
        const unsigned short* wb = Wt + (size_t)(((w * 4 + gv) * 2 + kh) * 32) * 512
                                      + (size_t)lane * 8;
        #pragma unroll
        for (int i = 0; i < 32; ++i)
            Bf[i] = *(const bf16x8*)(wb + i * 512);
    }
    // one-time: XW slice into LDS
    if (tid < 384) {
        int tok = tid >> 7, g = (tid >> 5) & 3, jl = tid & 31;
        xwl[tid] = XW[(tok * 4 + g) * HID + w * 32 + jl];
    }
    // one-time: token table into LDS (byte-packed)
    #pragma unroll
    for (int it = 0; it < 32; ++it) {
        int flat = it * 512 + tid;                 // 16384 tokens
        int row  = flat >> 9;
        int col  = flat & 511;
        xtok[flat] = (unsigned char)x[(grp * 32 + row) * T_SEQ + col];
    }
    __syncthreads();
    const bool use_local = (use_local_sh != 0);

    // elementwise ownership: thread -> row = tid>>4, cols jc2*2..+2
    const int erow = tid >> 4;
    const int jc2  = tid & 15;
    float cst[2] = {0.f, 0.f};
    unsigned long long* hs64 = (unsigned long long*)hs;

    for (int s = 0; s < T_SEQ; ++s) {
        // ---- wait for h(s) from all 32 group members (flags start at 0) ----
        if (s > 0) {
            if (wv == 0) {
                const int fidx = grp * 32 + (lane & 31);
                if (use_local) {
                    while (__hip_atomic_load(&flags[fidx], __ATOMIC_RELAXED,
                                             __HIP_MEMORY_SCOPE_AGENT) < s)
                        __builtin_amdgcn_s_sleep(1);
                } else {
                    while (__hip_atomic_load(&flags[fidx], __ATOMIC_RELAXED,
                                             __HIP_MEMORY_SCOPE_SYSTEM) < s)
                        __builtin_amdgcn_s_sleep(1);
                }
            }
            __syncthreads();
        }

        // ---- stage h(s)[32 rows x 256 qwords] into padded LDS ----
        const unsigned long long* hp64 = (const unsigned long long*)
            (hbuf32 + (size_t)(s & 1) * (BATCH * HID / 2)) + (size_t)grp * 32 * 256;
        {
            unsigned long long tmp[16];
            if (use_local) {
                #pragma unroll
                for (int it = 0; it < 16; ++it) {
                    int flat = it * 512 + tid;         // 8192 qwords
                    tmp[it] = __hip_atomic_load(&hp64[(flat >> 8) * 256 + (flat & 255)],
                                                __ATOMIC_RELAXED, __HIP_MEMORY_SCOPE_AGENT);
                }
            } else {
                #pragma unroll
                for (int it = 0; it < 16; ++it) {
                    int flat = it * 512 + tid;
                    tmp[it] = __hip_atomic_load(&hp64[(flat >> 8) * 256 + (flat & 255)],
                                                __ATOMIC_RELAXED, __HIP_MEMORY_SCOPE_SYSTEM);
                }
            }
            #pragma unroll
            for (int it = 0; it < 16; ++it) {
                int flat = it * 512 + tid;
                hs64[(flat >> 8) * 258 + (flat & 255)] = tmp[it];
            }
        }
        __syncthreads();

        // ---- GEMM: 32x32 tile for gate gv over K-half kh, B from registers ----
        floatx16 acc = {0.f,0.f,0.f,0.f,0.f,0.f,0.f,0.f,0.f,0.f,0.f,0.f,0.f,0.f,0.f,0.f};
        const unsigned short* ap = hs + m32 * 1032 + kh * 512 + hv5 * 8;
        #pragma unroll
        for (int i = 0; i < 32; ++i) {
            bf16x8 a = *(const bf16x8*)(ap + i * 16);
            acc = __builtin_amdgcn_mfma_f32_32x32x16_bf16(a, Bf[i], acc, 0, 0, 0);
        }

        // ---- scatter C (col=lane&31, row=(reg&3)+8*(reg>>2)+4*(lane>>5)) ----
        {
            float* gb = &gbuf[(size_t)(gv * 2 + kh) * 32 * 36];
            #pragma unroll
            for (int reg = 0; reg < 16; ++reg) {
                int row = (reg & 3) + 8 * (reg >> 2) + 4 * hv5;
                gb[row * 36 + m32] = acc[reg];
            }
        }
        __syncthreads();

        // ---- elementwise LSTM cell update, h(s+1) out ----
        {
            int tk = xtok[erow * 512 + s];
            const float* xb = &xwl[tk * 128];
            const int go = erow * 36 + jc2 * 2;
            floatx2 ag = *(const floatx2*)&gbuf[0 * 32 * 36 + go]
                       + *(const floatx2*)&gbuf[1 * 32 * 36 + go];
            floatx2 ai = *(const floatx2*)&gbuf[2 * 32 * 36 + go]
                       + *(const floatx2*)&gbuf[3 * 32 * 36 + go];
            floatx2 af = *(const floatx2*)&gbuf[4 * 32 * 36 + go]
                       + *(const floatx2*)&gbuf[5 * 32 * 36 + go];
            floatx2 ao = *(const floatx2*)&gbuf[6 * 32 * 36 + go]
                       + *(const floatx2*)&gbuf[7 * 32 * 36 + go];
            floatx2 xg = *(const floatx2*)&xb[0 * 32 + jc2 * 2];
            floatx2 xi = *(const floatx2*)&xb[1 * 32 + jc2 * 2];
            floatx2 xf = *(const floatx2*)&xb[2 * 32 + jc2 * 2];
            floatx2 xo = *(const floatx2*)&xb[3 * 32 + jc2 * 2];
            unsigned int hvv[2];
            #pragma unroll
            for (int u = 0; u < 2; ++u) {
                float g  = tanh_fast(ag[u] + xg[u]);
                float ii = sig_fast(ai[u] + xi[u]);
                float ff = sig_fast(af[u] + xf[u]);
                float oo = sig_fast(ao[u] + xo[u]);
                float cn = g * ii + cst[u] * ff;
                float h  = tanh_fast(cn) * oo;
                cst[u]   = (tk != 0) ? cn : 0.0f;   // pad = ((x+1)//2) in {0,1,1}
                hvv[u]   = f2bf(h);
            }
            unsigned int* hnext = hbuf32 + (size_t)((s + 1) & 1) * (BATCH * HID / 2);
            unsigned int* hp = &hnext[((grp * 32 + erow) * HID + w * 32 + jc2 * 2) >> 1];
            unsigned int hval = hvv[0] | (hvv[1] << 16);
            if (use_local) {
                // plain write-back store into the shared XCD L2 (no LLC RTT)
                __hip_atomic_store(hp, hval, __ATOMIC_RELAXED, __HIP_MEMORY_SCOPE_WORKGROUP);
            } else {
                __hip_atomic_store(hp, hval, __ATOMIC_RELAXED, __HIP_MEMORY_SCOPE_SYSTEM);
            }
        }
        // syncthreads drains each wave's vmcnt before s_barrier => on exit, all
        // h stores of this WG are complete at their coherence point (L2 local /
        // LLC fallback) before the flag is published.
        __syncthreads();

        if (s < T_SEQ - 1 && tid == 0) {
            if (use_local) {
                __hip_atomic_store(&flags[grp * 32 + w], s + 1,
                                   __ATOMIC_RELAXED, __HIP_MEMORY_SCOPE_WORKGROUP);
            } else {
                __hip_atomic_store(&flags[grp * 32 + w], s + 1,
                                   __ATOMIC_RELAXED, __HIP_MEMORY_SCOPE_SYSTEM);
            }
        }
    }
}

// -------------------- projection + log_softmax over batch dim ---------------
__global__ void proj_kernel(const unsigned short* __restrict__ h,
                            const float* __restrict__ wph, const float* __restrict__ bp,
                            float* __restrict__ out) {
    __shared__ float wl[HID * NCLS];
    __shared__ float red[256];
    int tid = threadIdx.x;      // = batch row
    for (int i = tid; i < HID * NCLS; i += 256) wl[i] = wph[i];
    __syncthreads();
    float p[NCLS];
    #pragma unroll
    for (int c2 = 0; c2 < NCLS; ++c2) p[c2] = bp[c2];
    const unsigned short* hr = h + tid * HID;
    for (int k0 = 0; k0 < HID / 8; ++k0) {
        bf16x8 hv = *(const bf16x8*)(hr + k0 * 8);
        #pragma unroll
        for (int j = 0; j < 8; ++j) {
            float hk = (float)hv[j];
            #pragma unroll
            for (int c2 = 0; c2 < NCLS; ++c2) p[c2] += hk * wl[(k0 * 8 + j) * NCLS + c2];
        }
    }
    for (int c2 = 0; c2 < NCLS; ++c2) {
        red[tid] = p[c2];
        __syncthreads();
        for (int s = 128; s > 0; s >>= 1) {
            if (tid < s) red[tid] = fmaxf(red[tid], red[tid + s]);
            __syncthreads();
        }
        float mx = red[0];
        __syncthreads();
        red[tid] = __expf(p[c2] - mx);
        __syncthreads();
        for (int s = 128; s > 0; s >>= 1) {
            if (tid < s) red[tid] += red[tid + s];
            __syncthreads();
        }
        float lse = mx + __logf(red[0]);
        __syncthreads();
        out[tid * NCLS + c2] = p[c2] - lse;
    }
}

// ----------------------------------------------------------------------------
extern "C" void kernel_launch(void* const* d_in, const int* in_sizes, int n_in,
                              void* d_out, int out_size, void* d_ws, size_t ws_size,
                              hipStream_t stream) {
    const int*   x    = (const int*)d_in[0];
    const float* emb  = (const float*)d_in[1];
    const float* wgx  = (const float*)d_in[2];
    const float* wgh  = (const float*)d_in[3];
    const float* bg_  = (const float*)d_in[4];
    const float* wix  = (const float*)d_in[5];
    const float* wih  = (const float*)d_in[6];
    const float* bi_  = (const float*)d_in[7];
    const float* wfx  = (const float*)d_in[8];
    const float* wfh  = (const float*)d_in[9];
    const float* bf_  = (const float*)d_in[10];
    const float* wox  = (const float*)d_in[11];
    const float* woh  = (const float*)d_in[12];
    const float* bo_  = (const float*)d_in[13];
    const float* wph  = (const float*)d_in[14];
    const float* bp_  = (const float*)d_in[15];
    float* out = (float*)d_out;

    char* wsp = (char*)d_ws;
    int*            flags = (int*)wsp;                                      // 4 KB
    int*            xflag = (int*)(wsp + 4096);                             // 4 KB
    float*          XW    = (float*)(wsp + 8192);                           // 48 KB
    unsigned short* Wt    = (unsigned short*)(wsp + 8192 + 49152);          // 8 MB
    unsigned int*   hbuf32= (unsigned int*)(wsp + 8192 + 49152 + 8388608);  // 1 MB

    hipMemsetAsync(flags, 0, 8192, stream);                                  // flags+xflag
    hipMemsetAsync(hbuf32, 0, BATCH * HID * sizeof(unsigned short), stream); // h0 = 0

    prep_xw_kernel<<<48, 256, 0, stream>>>(emb, wgx, wix, wfx, wox,
                                           bg_, bi_, bf_, bo_, XW);
    prep_w_kernel<<<8192, 64, 0, stream>>>(wgh, wih, wfh, woh, Wt);

    void* args[] = { (void*)&x, (void*)&XW, (void*)&Wt, (void*)&hbuf32,
                     (void*)&flags, (void*)&xflag };
    hipError_t cerr = hipLaunchCooperativeKernel((void*)lstm_kernel, dim3(256), dim3(512),
                                                 args, 0, stream);
    if (cerr != hipSuccess) {
        // Fallback: plain launch. The flag protocol needs only co-residency,
        // which grid=256 at 1 WG/CU provides.
        lstm_kernel<<<dim3(256), dim3(512), 0, stream>>>(x, XW, Wt, hbuf32, flags, xflag);
    }

    proj_kernel<<<1, 256, 0, stream>>>((const unsigned short*)hbuf32, wph, bp_, out);
}